// Round 3
// baseline (699.484 us; speedup 1.0000x reference)
//
#include <hip/hip_runtime.h>
#include <hip/hip_bf16.h>

// Problem constants (Mixtral attention prefill)
#define S_LEN 2048
#define HID 4096
#define NH 32
#define NKV 8
#define HD 128
#define NQKV 6144   // NH*HD + 2*NKV*HD

typedef unsigned short u16;
typedef unsigned int u32;
typedef __bf16 bf16x8 __attribute__((ext_vector_type(8)));
typedef float f32x4 __attribute__((ext_vector_type(4)));

__device__ __forceinline__ float bf2f(u16 u) {
    union { u32 i; float f; } x; x.i = ((u32)u) << 16; return x.f;
}
__device__ __forceinline__ u16 f2bf(float f) {
    union { float f; u32 i; } x; x.f = f;
    u32 r = x.i + 0x7fffu + ((x.i >> 16) & 1u);   // RNE
    return (u16)(r >> 16);
}
__device__ __forceinline__ u32 pack2(float a, float b) {
    return (u32)f2bf(a) | ((u32)f2bf(b) << 16);
}
// async global->LDS, 16 B per lane; LDS dest is wave-uniform base + lane*16
__device__ __forceinline__ void gld16(const u16* g, u16* l) {
    __builtin_amdgcn_global_load_lds(
        (const __attribute__((address_space(1))) u32*)g,
        (__attribute__((address_space(3))) u32*)l, 16, 0, 0);
}

// ---------------------------------------------------------------------------
// fp32 -> bf16 convert (8 elems/thread), n8 = n/8
// ---------------------------------------------------------------------------
__global__ __launch_bounds__(256) void cvt_f32_bf16(
    const float* __restrict__ src, u16* __restrict__ dst, int n8)
{
    int i = blockIdx.x * 256 + threadIdx.x;
    if (i >= n8) return;
    const float4* s = (const float4*)src + (size_t)i * 2;
    float4 x0 = s[0], x1 = s[1];
    uint4 p;
    p.x = pack2(x0.x, x0.y); p.y = pack2(x0.z, x0.w);
    p.z = pack2(x1.x, x1.y); p.w = pack2(x1.z, x1.w);
    *((uint4*)dst + i) = p;
}

// ---------------------------------------------------------------------------
// m97-style GEMM: C[M][N] = X[M][K] * W[N][K]^T, all bf16, fp32 acc.
// 128x128 tile, BK=32, 4 waves in 2x2; 4x4 16x16 C-tiles per wave.
// Staging via global_load_lds width=16 (contiguous LDS, no padding).
// T1: XCD-aware bijective block swizzle (grids here are %8==0).
// ---------------------------------------------------------------------------
template <bool OUTBF16>
__global__ __launch_bounds__(256) void gemm128(
    const u16* __restrict__ X, const u16* __restrict__ W,
    void* __restrict__ C, int K, int ldc)
{
    __shared__ __align__(16) u16 As[128 * 32];   // 8 KB
    __shared__ __align__(16) u16 Bs[128 * 32];   // 8 KB

    const int tid  = threadIdx.x;
    const int w    = tid >> 6;
    const int lane = tid & 63;
    const int quad = lane >> 4;
    const int n16  = lane & 15;

    int id = blockIdx.y * gridDim.x + blockIdx.x;
    const int nwg = gridDim.x * gridDim.y;
    if ((nwg & 7) == 0) {
        const int cpx = nwg >> 3;
        id = (id & 7) * cpx + (id >> 3);
    }
    const int m0 = (id / gridDim.x) * 128;
    const int n0 = (id % gridDim.x) * 128;

    const int wr   = (w >> 1) * 64;
    const int wc   = (w & 1) * 64;

    const int c0 = tid;          // staging chunk ids: row=c>>2, koff=(c&3)*8
    const int c1 = tid + 256;

    f32x4 acc[4][4] = {};

    for (int k0 = 0; k0 < K; k0 += 32) {
        __syncthreads();
        // A tile: 128 rows x 32 k (8 KB) in 512 16B chunks
        gld16(X + (size_t)(m0 + (c0 >> 2)) * K + k0 + (c0 & 3) * 8,
              As + (size_t)(w * 64) * 8);
        gld16(X + (size_t)(m0 + (c1 >> 2)) * K + k0 + (c1 & 3) * 8,
              As + (size_t)(256 + w * 64) * 8);
        // B tile
        gld16(W + (size_t)(n0 + (c0 >> 2)) * K + k0 + (c0 & 3) * 8,
              Bs + (size_t)(w * 64) * 8);
        gld16(W + (size_t)(n0 + (c1 >> 2)) * K + k0 + (c1 & 3) * 8,
              Bs + (size_t)(256 + w * 64) * 8);
        __syncthreads();

        bf16x8 a[4], b[4];
#pragma unroll
        for (int t = 0; t < 4; ++t) {
            a[t] = *reinterpret_cast<const bf16x8*>(As + (wr + t * 16 + n16) * 32 + quad * 8);
            b[t] = *reinterpret_cast<const bf16x8*>(Bs + (wc + t * 16 + n16) * 32 + quad * 8);
        }
#pragma unroll
        for (int mt = 0; mt < 4; ++mt)
#pragma unroll
            for (int nt = 0; nt < 4; ++nt)
                acc[mt][nt] = __builtin_amdgcn_mfma_f32_16x16x32_bf16(
                    a[mt], b[nt], acc[mt][nt], 0, 0, 0);
    }

#pragma unroll
    for (int mt = 0; mt < 4; ++mt) {
        const int row0 = m0 + wr + mt * 16 + quad * 4;
#pragma unroll
        for (int nt = 0; nt < 4; ++nt) {
            const int col = n0 + wc + nt * 16 + n16;
#pragma unroll
            for (int r = 0; r < 4; ++r) {
                if constexpr (OUTBF16)
                    ((u16*)C)[(size_t)(row0 + r) * ldc + col] = f2bf(acc[mt][nt][r]);
                else
                    ((float*)C)[(size_t)(row0 + r) * ldc + col] = acc[mt][nt][r];
            }
        }
    }
}

// ---------------------------------------------------------------------------
// Fallback GEMM (R3): fp32 inputs converted on the fly, 64x64 tile.
// ---------------------------------------------------------------------------
template <bool XF32, bool OUTBF16>
__global__ __launch_bounds__(256) void gemm_bt(
    const void* __restrict__ Xv,
    const float* __restrict__ W0, int r1,
    const float* __restrict__ W1, int r2,
    const float* __restrict__ W2,
    void* __restrict__ C, int K, int ldc)
{
    __shared__ u16 Xs[64][48];
    __shared__ u16 Ws[64][48];

    const int tid  = threadIdx.x;
    const int w    = tid >> 6;
    const int lane = tid & 63;
    const int m0   = blockIdx.y * 64;
    const int n0   = blockIdx.x * 64;

    const int sr = tid >> 2;
    const int sc = (tid & 3) * 8;

    const float* xrow32 = nullptr;
    const u16*   xrow16 = nullptr;
    if constexpr (XF32) xrow32 = (const float*)Xv + (size_t)(m0 + sr) * K;
    else                xrow16 = (const u16*)Xv + (size_t)(m0 + sr) * K;

    const int wr = n0 + sr;
    const float* wrow;
    if (wr < r1)      wrow = W0 + (size_t)wr * K;
    else if (wr < r2) wrow = W1 + (size_t)(wr - r1) * K;
    else              wrow = W2 + (size_t)(wr - r2) * K;

    f32x4 acc[4] = {};
    const int mrow = w * 16 + (lane & 15);
    const int nrow = lane & 15;
    const int kq   = (lane >> 4) * 8;

    for (int k0 = 0; k0 < K; k0 += 32) {
        __syncthreads();
        if constexpr (XF32) {
            float4 x0 = *reinterpret_cast<const float4*>(xrow32 + k0 + sc);
            float4 x1 = *reinterpret_cast<const float4*>(xrow32 + k0 + sc + 4);
            uint4 p;
            p.x = pack2(x0.x, x0.y); p.y = pack2(x0.z, x0.w);
            p.z = pack2(x1.x, x1.y); p.w = pack2(x1.z, x1.w);
            *reinterpret_cast<uint4*>(&Xs[sr][sc]) = p;
        } else {
            *reinterpret_cast<uint4*>(&Xs[sr][sc]) =
                *reinterpret_cast<const uint4*>(xrow16 + k0 + sc);
        }
        {
            float4 w0v = *reinterpret_cast<const float4*>(wrow + k0 + sc);
            float4 w1v = *reinterpret_cast<const float4*>(wrow + k0 + sc + 4);
            uint4 p;
            p.x = pack2(w0v.x, w0v.y); p.y = pack2(w0v.z, w0v.w);
            p.z = pack2(w1v.x, w1v.y); p.w = pack2(w1v.z, w1v.w);
            *reinterpret_cast<uint4*>(&Ws[sr][sc]) = p;
        }
        __syncthreads();
        bf16x8 a = *reinterpret_cast<const bf16x8*>(&Xs[mrow][kq]);
#pragma unroll
        for (int t = 0; t < 4; ++t) {
            bf16x8 b = *reinterpret_cast<const bf16x8*>(&Ws[t * 16 + nrow][kq]);
            acc[t] = __builtin_amdgcn_mfma_f32_16x16x32_bf16(a, b, acc[t], 0, 0, 0);
        }
    }

    const int mb = m0 + w * 16 + ((lane >> 4) << 2);
#pragma unroll
    for (int t = 0; t < 4; ++t) {
        const int col = n0 + t * 16 + (lane & 15);
#pragma unroll
        for (int i = 0; i < 4; ++i) {
            if constexpr (OUTBF16)
                ((u16*)C)[(size_t)(mb + i) * ldc + col] = f2bf(acc[t][i]);
            else
                ((float*)C)[(size_t)(mb + i) * ldc + col] = acc[t][i];
        }
    }
}

// ---------------------------------------------------------------------------
// RoPE (half-split, theta=1e6); Q pre-scaled by 1/sqrt(HD).
// ---------------------------------------------------------------------------
__global__ __launch_bounds__(256) void rope_kernel(
    const u16* __restrict__ qkv, const int* __restrict__ pos,
    u16* __restrict__ qb, u16* __restrict__ kb, u16* __restrict__ vb)
{
    const int n   = blockIdx.x;
    const int tid = threadIdx.x;
    const float scale = 0.08838834764831845f;
    __shared__ float cs[64], sn[64];
    if (tid < 64) {
        float p   = (float)pos[n];
        float inv = powf(1.0e6f, -(float)tid / 64.0f);
        float f   = p * inv;
        cs[tid] = cosf(f);
        sn[tid] = sinf(f);
    }
    __syncthreads();
    const u16* row = qkv + (size_t)n * NQKV;

    for (int i = tid; i < NH * 64; i += 256) {
        int h = i >> 6, j = i & 63;
        float x1 = bf2f(row[h * HD + j]), x2 = bf2f(row[h * HD + j + 64]);
        size_t base = ((size_t)h * S_LEN + n) * HD;
        qb[base + j]      = f2bf((x1 * cs[j] - x2 * sn[j]) * scale);
        qb[base + j + 64] = f2bf((x2 * cs[j] + x1 * sn[j]) * scale);
    }
    for (int i = tid; i < NKV * 64; i += 256) {
        int g = i >> 6, j = i & 63;
        const u16* kr = row + NH * HD + g * HD;
        float x1 = bf2f(kr[j]), x2 = bf2f(kr[j + 64]);
        size_t base = ((size_t)g * S_LEN + n) * HD;
        kb[base + j]      = f2bf(x1 * cs[j] - x2 * sn[j]);
        kb[base + j + 64] = f2bf(x2 * cs[j] + x1 * sn[j]);
    }
    for (int i = tid; i < NKV * HD; i += 256) {
        int g = i >> 7, d = i & 127;
        vb[((size_t)g * S_LEN + n) * HD + d] = row[NH * HD + NKV * HD + g * HD + d];
    }
}

// ---------------------------------------------------------------------------
// MFMA flash attention (causal GQA).
// R5: q-tile pairing (i, 31-i) for uniform causal work.
// R6: XOR-swizzled LDS, P aliased into K buffer, reg-prefetch staging.
// R7: in-block split-K with 8 waves (512 thr). Waves 0-3 = even K-tiles,
//     waves 4-7 = odd K-tiles; separate LDS buffers + online-softmax state;
//     merged via LDS at the end of each q-tile. Grid stays 512 blocks but
//     waves/CU double (8 -> 16, occupancy 25% -> 50% structural), and
//     per-block sequential iterations halve (33 -> 17).
// ---------------------------------------------------------------------------
__global__ __launch_bounds__(512, 4) void attn_mfma(
    const u16* __restrict__ qb, const u16* __restrict__ kb,
    const u16* __restrict__ vb, u16* __restrict__ ao)
{
    // 64 KB: KPs[2] (16 KB each, P aliases low 8 KB), Vt[2] (16 KB each)
    __shared__ __align__(16) u16 smem[32768];

    const int tid  = threadIdx.x;
    const int gtid = tid & 255;        // id within group
    const int grp  = tid >> 8;         // 0: even tiles, 1: odd tiles
    const int wg   = (tid >> 6) & 3;   // wave within group
    const int lane = tid & 63;
    const int quad = lane >> 4;
    const int n16  = lane & 15;
    const int h    = blockIdx.y;
    const int g    = h >> 2;
    const int NQT  = S_LEN / 64;       // 32 q-tiles

    u16* KPg = smem + grp * 8192;            // 64 x 128 (stride 128)
    u16* Vtg = smem + 16384 + grp * 8192;    // 128 x 64 (stride 64)
    float* mb = reinterpret_cast<float*>(smem);  // merge buffer (40 KB)

    const u16* kbase = kb + (size_t)g * S_LEN * HD;
    const u16* vbase = vb + (size_t)g * S_LEN * HD;
    const int xsw = (n16 & 7) << 3;   // read-side XOR swizzle (u16 units)

    for (int half = 0; half < 2; ++half) {
        const int qt = half ? (NQT - 1 - blockIdx.x) : blockIdx.x;
        const int q0 = qt * 64;

        bf16x8 qf[4];
        {
            const u16* qrow = qb + ((size_t)h * S_LEN + q0 + wg * 16 + n16) * HD;
#pragma unroll
            for (int s = 0; s < 4; ++s)
                qf[s] = *reinterpret_cast<const bf16x8*>(qrow + s * 32 + quad * 8);
        }

        f32x4 of[8] = {};
        float mrow[4], lrow[4];
#pragma unroll
        for (int r = 0; r < 4; ++r) { mrow[r] = -1e30f; lrow[r] = 0.0f; }

        uint4 kreg[4], vreg[4];
        auto load_kv = [&](int k0) {
#pragma unroll
            for (int i = 0; i < 4; ++i) {
                kreg[i] = *reinterpret_cast<const uint4*>(
                    kbase + (size_t)(k0 + (gtid >> 4) + 16 * i) * HD + (gtid & 15) * 8);
                vreg[i] = *reinterpret_cast<const uint4*>(
                    vbase + (size_t)(k0 + lane) * HD + wg * 8 + i * 32);
            }
        };
        load_kv(grp * 64);   // prologue (always in-bounds; unused if inactive)

        const int ntiles = qt + 1;
        const int nIt = (ntiles + 1) >> 1;
        for (int it = 0; it < nIt; ++it) {
            const int kt = 2 * it + grp;
            const bool act = (kt < ntiles);

            __syncthreads();   // prev tile's PV reads done; LDS free
            if (act) {
                // K regs -> LDS (swizzled)
#pragma unroll
                for (int i = 0; i < 4; ++i) {
                    const int key = (gtid >> 4) + 16 * i;
                    const int d0  = (gtid & 15) * 8;
                    *reinterpret_cast<uint4*>(
                        &KPg[key * 128 + (d0 ^ ((key & 7) << 3))]) = kreg[i];
                }
                // V regs -> LDS transposed (swizzled)
#pragma unroll
                for (int i = 0; i < 4; ++i) {
                    const int d0 = wg * 8 + i * 32;
                    const u32 vw[4] = {vreg[i].x, vreg[i].y, vreg[i].z, vreg[i].w};
#pragma unroll
                    for (int t = 0; t < 4; ++t) {
                        const int r0 = d0 + 2 * t;
                        Vtg[r0 * 64 + (lane ^ ((r0 & 7) << 3))]             = (u16)(vw[t] & 0xffff);
                        Vtg[(r0 + 1) * 64 + (lane ^ (((r0 + 1) & 7) << 3))] = (u16)(vw[t] >> 16);
                    }
                }
            }
            __syncthreads();
            // prefetch this group's next tile (kt+2) under compute
            if (kt + 2 < ntiles) load_kv((kt + 2) * 64);

            f32x4 sc[4] = {};
            if (act) {
#pragma unroll
                for (int s = 0; s < 4; ++s) {
#pragma unroll
                    for (int t = 0; t < 4; ++t) {
                        bf16x8 bf = *reinterpret_cast<const bf16x8*>(
                            &KPg[(t * 16 + n16) * 128 + ((s * 32 + quad * 8) ^ xsw)]);
                        sc[t] = __builtin_amdgcn_mfma_f32_16x16x32_bf16(qf[s], bf, sc[t], 0, 0, 0);
                    }
                }
                if (kt == qt) {   // diagonal tile: causal mask
                    const int qbase = q0 + wg * 16 + quad * 4;
#pragma unroll
                    for (int t = 0; t < 4; ++t) {
                        int key = kt * 64 + t * 16 + n16;
#pragma unroll
                        for (int r = 0; r < 4; ++r)
                            if (key > qbase + r) sc[t][r] = -1e30f;
                    }
                }
            }

            __syncthreads();   // group's waves done reading K; P may overwrite

            if (act) {
#pragma unroll
                for (int r = 0; r < 4; ++r) {
                    float mx = fmaxf(fmaxf(sc[0][r], sc[1][r]), fmaxf(sc[2][r], sc[3][r]));
                    mx = fmaxf(mx, __shfl_xor(mx, 1));
                    mx = fmaxf(mx, __shfl_xor(mx, 2));
                    mx = fmaxf(mx, __shfl_xor(mx, 4));
                    mx = fmaxf(mx, __shfl_xor(mx, 8));
                    float mnew  = fmaxf(mrow[r], mx);
                    float alpha = __expf(mrow[r] - mnew);
                    float ls = 0.0f;
                    const int pr = quad * 4 + r;
#pragma unroll
                    for (int t = 0; t < 4; ++t) {
                        float p = __expf(sc[t][r] - mnew);
                        KPg[(wg * 16 + pr) * 64 + ((t * 16 + n16) ^ ((pr & 7) << 3))] = f2bf(p);
                        ls += p;
                    }
                    ls += __shfl_xor(ls, 1);
                    ls += __shfl_xor(ls, 2);
                    ls += __shfl_xor(ls, 4);
                    ls += __shfl_xor(ls, 8);
                    lrow[r] = lrow[r] * alpha + ls;
                    mrow[r] = mnew;
#pragma unroll
                    for (int nt = 0; nt < 8; ++nt) of[nt][r] *= alpha;
                }
                __threadfence_block();

#pragma unroll
                for (int s = 0; s < 2; ++s) {
                    bf16x8 af = *reinterpret_cast<const bf16x8*>(
                        &KPg[(wg * 16 + n16) * 64 + ((s * 32 + quad * 8) ^ xsw)]);
#pragma unroll
                    for (int nt = 0; nt < 8; ++nt) {
                        bf16x8 bf = *reinterpret_cast<const bf16x8*>(
                            &Vtg[(nt * 16 + n16) * 64 + ((s * 32 + quad * 8) ^ xsw)]);
                        of[nt] = __builtin_amdgcn_mfma_f32_16x16x32_bf16(af, bf, of[nt], 0, 0, 0);
                    }
                }
            }
        }

        // ---- merge the two groups' online-softmax partials, group 0 writes out
        __syncthreads();   // all PV reads done; LDS reusable as merge buffer
        if (grp == 1) {
            float* dst = mb + ((size_t)(wg * 64 + lane)) * 40;
#pragma unroll
            for (int nt = 0; nt < 8; ++nt)
#pragma unroll
                for (int r = 0; r < 4; ++r) dst[nt * 4 + r] = of[nt][r];
#pragma unroll
            for (int r = 0; r < 4; ++r) { dst[32 + r] = mrow[r]; dst[36 + r] = lrow[r]; }
        }
        __syncthreads();
        if (grp == 0) {
            const float* src = mb + ((size_t)(wg * 64 + lane)) * 40;
#pragma unroll
            for (int r = 0; r < 4; ++r) {
                const float mB = src[32 + r], lB = src[36 + r];
                const float m  = fmaxf(mrow[r], mB);
                const float a  = __expf(mrow[r] - m);
                const float b  = __expf(mB - m);
                const float inv = 1.0f / (lrow[r] * a + lB * b);
                u16* dst = ao + (size_t)(q0 + wg * 16 + quad * 4 + r) * (NH * HD) + h * HD + n16;
#pragma unroll
                for (int nt = 0; nt < 8; ++nt)
                    dst[nt * 16] = f2bf((of[nt][r] * a + src[nt * 4 + r] * b) * inv);
            }
        }
        __syncthreads();   // merge reads done before next half's staging
    }
}

// ---------------------------------------------------------------------------
// Fast-path workspace overlay (bytes), peak 92,274,688:
//   hb   [2048][4096] bf16 @ 0           (16.8M)  -> reused as qb after gemm1
//   wqkv [6144][4096] bf16 @ 16,777,216  (50.3M)  -> dead after gemm1:
//        ao @ 16,777,216 (16.8M) | kb @ 33,554,432 | vb @ 37,748,736
//   wo_b [4096][4096] bf16 @ 41,943,040  (33.5M)
//   qkv  [2048][6144] bf16 @ 67,108,864  (25.2M)  -> dead after rope
// ---------------------------------------------------------------------------
extern "C" void kernel_launch(void* const* d_in, const int* in_sizes, int n_in,
                              void* d_out, int out_size, void* d_ws, size_t ws_size,
                              hipStream_t stream)
{
    const float* h   = (const float*)d_in[0];
    const int*   pos = (const int*)d_in[1];
    const float* wq  = (const float*)d_in[2];
    const float* wk  = (const float*)d_in[3];
    const float* wv  = (const float*)d_in[4];
    const float* wo  = (const float*)d_in[5];

    char* ws = (char*)d_ws;

    if (ws_size >= 92274688ull) {
        // ---- fast path: bf16 weight pre-convert + 128-tile global_load_lds GEMM
        u16* hb     = (u16*)(ws);
        u16* wqkv_b = (u16*)(ws + 16777216);
        u16* ao     = (u16*)(ws + 16777216);
        u16* kb     = (u16*)(ws + 33554432);
        u16* vb     = (u16*)(ws + 37748736);
        u16* wo_b   = (u16*)(ws + 41943040);
        u16* qkv    = (u16*)(ws + 67108864);
        u16* qb     = hb;

        cvt_f32_bf16<<<4096, 256, 0, stream>>>(h, hb, 1048576);          // 8.4M elems
        cvt_f32_bf16<<<8192, 256, 0, stream>>>(wq, wqkv_b, 2097152);     // 16.8M
        cvt_f32_bf16<<<2048, 256, 0, stream>>>(wk, wqkv_b + 16777216, 524288);
        cvt_f32_bf16<<<2048, 256, 0, stream>>>(wv, wqkv_b + 20971520, 524288);

        gemm128<true><<<dim3(NQKV / 128, S_LEN / 128), 256, 0, stream>>>(
            hb, wqkv_b, qkv, HID, NQKV);
        rope_kernel<<<S_LEN, 256, 0, stream>>>(qkv, pos, qb, kb, vb);
        cvt_f32_bf16<<<8192, 256, 0, stream>>>(wo, wo_b, 2097152);       // 16.8M
        attn_mfma<<<dim3(S_LEN / 128, NH), 512, 0, stream>>>(qb, kb, vb, ao);
        gemm128<false><<<dim3(HID / 128, S_LEN / 128), 256, 0, stream>>>(
            ao, wo_b, d_out, NH * HD, HID);
    } else {
        // ---- fallback (R3 layout, 64 MB)
        u16* qkv = (u16*)(ws);
        u16* qb  = (u16*)(ws + 25165824);
        u16* kb  = (u16*)(ws + 41943040);
        u16* vb  = (u16*)(ws + 46137344);
        u16* ao  = (u16*)(ws + 50331648);

        dim3 g1(NQKV / 64, S_LEN / 64);
        gemm_bt<true, true><<<g1, 256, 0, stream>>>(
            h, wq, NH * HD, wk, NH * HD + NKV * HD, wv, qkv, HID, NQKV);
        rope_kernel<<<S_LEN, 256, 0, stream>>>(qkv, pos, qb, kb, vb);
        attn_mfma<<<dim3(S_LEN / 128, NH), 512, 0, stream>>>(qb, kb, vb, ao);
        dim3 g2(HID / 64, S_LEN / 64);
        gemm_bt<false, false><<<g2, 256, 0, stream>>>(
            ao, wo, HID, wo, HID, wo, d_out, NH * HD, HID);
    }
}

// Round 5
// 568.221 us; speedup vs baseline: 1.2310x; 1.2310x over previous
//
#include <hip/hip_runtime.h>
#include <hip/hip_bf16.h>

// Problem constants (Mixtral attention prefill)
#define S_LEN 2048
#define HID 4096
#define NH 32
#define NKV 8
#define HD 128
#define NQKV 6144   // NH*HD + 2*NKV*HD

typedef unsigned short u16;
typedef unsigned int u32;
typedef __bf16 bf16x8 __attribute__((ext_vector_type(8)));
typedef float f32x4 __attribute__((ext_vector_type(4)));

__device__ __forceinline__ float bf2f(u16 u) {
    union { u32 i; float f; } x; x.i = ((u32)u) << 16; return x.f;
}
__device__ __forceinline__ u16 f2bf(float f) {
    union { float f; u32 i; } x; x.f = f;
    u32 r = x.i + 0x7fffu + ((x.i >> 16) & 1u);   // RNE
    return (u16)(r >> 16);
}
__device__ __forceinline__ u32 pack2(float a, float b) {
    return (u32)f2bf(a) | ((u32)f2bf(b) << 16);
}
// async global->LDS, 16 B per lane; LDS dest is wave-uniform base + lane*16
__device__ __forceinline__ void gld16(const u16* g, u16* l) {
    __builtin_amdgcn_global_load_lds(
        (const __attribute__((address_space(1))) u32*)g,
        (__attribute__((address_space(3))) u32*)l, 16, 0, 0);
}

// ---------------------------------------------------------------------------
// fp32 -> bf16 convert (8 elems/thread), n8 = n/8
// ---------------------------------------------------------------------------
__global__ __launch_bounds__(256) void cvt_f32_bf16(
    const float* __restrict__ src, u16* __restrict__ dst, int n8)
{
    int i = blockIdx.x * 256 + threadIdx.x;
    if (i >= n8) return;
    const float4* s = (const float4*)src + (size_t)i * 2;
    float4 x0 = s[0], x1 = s[1];
    uint4 p;
    p.x = pack2(x0.x, x0.y); p.y = pack2(x0.z, x0.w);
    p.z = pack2(x1.x, x1.y); p.w = pack2(x1.z, x1.w);
    *((uint4*)dst + i) = p;
}

// ---------------------------------------------------------------------------
// m97-style GEMM: C[M][N] = X[M][K] * W[N][K]^T, all bf16, fp32 acc.
// 128x128 tile, BK=32, 4 waves in 2x2; 4x4 16x16 C-tiles per wave.
// Staging via global_load_lds width=16 (contiguous LDS, no padding).
// T1: XCD-aware bijective block swizzle (grids here are %8==0).
// ---------------------------------------------------------------------------
template <bool OUTBF16>
__global__ __launch_bounds__(256) void gemm128(
    const u16* __restrict__ X, const u16* __restrict__ W,
    void* __restrict__ C, int K, int ldc)
{
    __shared__ __align__(16) u16 As[128 * 32];   // 8 KB
    __shared__ __align__(16) u16 Bs[128 * 32];   // 8 KB

    const int tid  = threadIdx.x;
    const int w    = tid >> 6;
    const int lane = tid & 63;
    const int quad = lane >> 4;
    const int n16  = lane & 15;

    int id = blockIdx.y * gridDim.x + blockIdx.x;
    const int nwg = gridDim.x * gridDim.y;
    if ((nwg & 7) == 0) {
        const int cpx = nwg >> 3;
        id = (id & 7) * cpx + (id >> 3);
    }
    const int m0 = (id / gridDim.x) * 128;
    const int n0 = (id % gridDim.x) * 128;

    const int wr   = (w >> 1) * 64;
    const int wc   = (w & 1) * 64;

    const int c0 = tid;          // staging chunk ids: row=c>>2, koff=(c&3)*8
    const int c1 = tid + 256;

    f32x4 acc[4][4] = {};

    for (int k0 = 0; k0 < K; k0 += 32) {
        __syncthreads();
        // A tile: 128 rows x 32 k (8 KB) in 512 16B chunks
        gld16(X + (size_t)(m0 + (c0 >> 2)) * K + k0 + (c0 & 3) * 8,
              As + (size_t)(w * 64) * 8);
        gld16(X + (size_t)(m0 + (c1 >> 2)) * K + k0 + (c1 & 3) * 8,
              As + (size_t)(256 + w * 64) * 8);
        // B tile
        gld16(W + (size_t)(n0 + (c0 >> 2)) * K + k0 + (c0 & 3) * 8,
              Bs + (size_t)(w * 64) * 8);
        gld16(W + (size_t)(n0 + (c1 >> 2)) * K + k0 + (c1 & 3) * 8,
              Bs + (size_t)(256 + w * 64) * 8);
        __syncthreads();

        bf16x8 a[4], b[4];
#pragma unroll
        for (int t = 0; t < 4; ++t) {
            a[t] = *reinterpret_cast<const bf16x8*>(As + (wr + t * 16 + n16) * 32 + quad * 8);
            b[t] = *reinterpret_cast<const bf16x8*>(Bs + (wc + t * 16 + n16) * 32 + quad * 8);
        }
#pragma unroll
        for (int mt = 0; mt < 4; ++mt)
#pragma unroll
            for (int nt = 0; nt < 4; ++nt)
                acc[mt][nt] = __builtin_amdgcn_mfma_f32_16x16x32_bf16(
                    a[mt], b[nt], acc[mt][nt], 0, 0, 0);
    }

#pragma unroll
    for (int mt = 0; mt < 4; ++mt) {
        const int row0 = m0 + wr + mt * 16 + quad * 4;
#pragma unroll
        for (int nt = 0; nt < 4; ++nt) {
            const int col = n0 + wc + nt * 16 + n16;
#pragma unroll
            for (int r = 0; r < 4; ++r) {
                if constexpr (OUTBF16)
                    ((u16*)C)[(size_t)(row0 + r) * ldc + col] = f2bf(acc[mt][nt][r]);
                else
                    ((float*)C)[(size_t)(row0 + r) * ldc + col] = acc[mt][nt][r];
            }
        }
    }
}

// ---------------------------------------------------------------------------
// Fallback GEMM (R3): fp32 inputs converted on the fly, 64x64 tile.
// ---------------------------------------------------------------------------
template <bool XF32, bool OUTBF16>
__global__ __launch_bounds__(256) void gemm_bt(
    const void* __restrict__ Xv,
    const float* __restrict__ W0, int r1,
    const float* __restrict__ W1, int r2,
    const float* __restrict__ W2,
    void* __restrict__ C, int K, int ldc)
{
    __shared__ u16 Xs[64][48];
    __shared__ u16 Ws[64][48];

    const int tid  = threadIdx.x;
    const int w    = tid >> 6;
    const int lane = tid & 63;
    const int m0   = blockIdx.y * 64;
    const int n0   = blockIdx.x * 64;

    const int sr = tid >> 2;
    const int sc = (tid & 3) * 8;

    const float* xrow32 = nullptr;
    const u16*   xrow16 = nullptr;
    if constexpr (XF32) xrow32 = (const float*)Xv + (size_t)(m0 + sr) * K;
    else                xrow16 = (const u16*)Xv + (size_t)(m0 + sr) * K;

    const int wr = n0 + sr;
    const float* wrow;
    if (wr < r1)      wrow = W0 + (size_t)wr * K;
    else if (wr < r2) wrow = W1 + (size_t)(wr - r1) * K;
    else              wrow = W2 + (size_t)(wr - r2) * K;

    f32x4 acc[4] = {};
    const int mrow = w * 16 + (lane & 15);
    const int nrow = lane & 15;
    const int kq   = (lane >> 4) * 8;

    for (int k0 = 0; k0 < K; k0 += 32) {
        __syncthreads();
        if constexpr (XF32) {
            float4 x0 = *reinterpret_cast<const float4*>(xrow32 + k0 + sc);
            float4 x1 = *reinterpret_cast<const float4*>(xrow32 + k0 + sc + 4);
            uint4 p;
            p.x = pack2(x0.x, x0.y); p.y = pack2(x0.z, x0.w);
            p.z = pack2(x1.x, x1.y); p.w = pack2(x1.z, x1.w);
            *reinterpret_cast<uint4*>(&Xs[sr][sc]) = p;
        } else {
            *reinterpret_cast<uint4*>(&Xs[sr][sc]) =
                *reinterpret_cast<const uint4*>(xrow16 + k0 + sc);
        }
        {
            float4 w0v = *reinterpret_cast<const float4*>(wrow + k0 + sc);
            float4 w1v = *reinterpret_cast<const float4*>(wrow + k0 + sc + 4);
            uint4 p;
            p.x = pack2(w0v.x, w0v.y); p.y = pack2(w0v.z, w0v.w);
            p.z = pack2(w1v.x, w1v.y); p.w = pack2(w1v.z, w1v.w);
            *reinterpret_cast<uint4*>(&Ws[sr][sc]) = p;
        }
        __syncthreads();
        bf16x8 a = *reinterpret_cast<const bf16x8*>(&Xs[mrow][kq]);
#pragma unroll
        for (int t = 0; t < 4; ++t) {
            bf16x8 b = *reinterpret_cast<const bf16x8*>(&Ws[t * 16 + nrow][kq]);
            acc[t] = __builtin_amdgcn_mfma_f32_16x16x32_bf16(a, b, acc[t], 0, 0, 0);
        }
    }

    const int mb = m0 + w * 16 + ((lane >> 4) << 2);
#pragma unroll
    for (int t = 0; t < 4; ++t) {
        const int col = n0 + t * 16 + (lane & 15);
#pragma unroll
        for (int i = 0; i < 4; ++i) {
            if constexpr (OUTBF16)
                ((u16*)C)[(size_t)(mb + i) * ldc + col] = f2bf(acc[t][i]);
            else
                ((float*)C)[(size_t)(mb + i) * ldc + col] = acc[t][i];
        }
    }
}

// ---------------------------------------------------------------------------
// RoPE (half-split, theta=1e6); Q pre-scaled by 1/sqrt(HD).
// ---------------------------------------------------------------------------
__global__ __launch_bounds__(256) void rope_kernel(
    const u16* __restrict__ qkv, const int* __restrict__ pos,
    u16* __restrict__ qb, u16* __restrict__ kb, u16* __restrict__ vb)
{
    const int n   = blockIdx.x;
    const int tid = threadIdx.x;
    const float scale = 0.08838834764831845f;
    __shared__ float cs[64], sn[64];
    if (tid < 64) {
        float p   = (float)pos[n];
        float inv = powf(1.0e6f, -(float)tid / 64.0f);
        float f   = p * inv;
        cs[tid] = cosf(f);
        sn[tid] = sinf(f);
    }
    __syncthreads();
    const u16* row = qkv + (size_t)n * NQKV;

    for (int i = tid; i < NH * 64; i += 256) {
        int h = i >> 6, j = i & 63;
        float x1 = bf2f(row[h * HD + j]), x2 = bf2f(row[h * HD + j + 64]);
        size_t base = ((size_t)h * S_LEN + n) * HD;
        qb[base + j]      = f2bf((x1 * cs[j] - x2 * sn[j]) * scale);
        qb[base + j + 64] = f2bf((x2 * cs[j] + x1 * sn[j]) * scale);
    }
    for (int i = tid; i < NKV * 64; i += 256) {
        int g = i >> 6, j = i & 63;
        const u16* kr = row + NH * HD + g * HD;
        float x1 = bf2f(kr[j]), x2 = bf2f(kr[j + 64]);
        size_t base = ((size_t)g * S_LEN + n) * HD;
        kb[base + j]      = f2bf(x1 * cs[j] - x2 * sn[j]);
        kb[base + j + 64] = f2bf(x2 * cs[j] + x1 * sn[j]);
    }
    for (int i = tid; i < NKV * HD; i += 256) {
        int g = i >> 7, d = i & 127;
        vb[((size_t)g * S_LEN + n) * HD + d] = row[NH * HD + NKV * HD + g * HD + d];
    }
}

// ---------------------------------------------------------------------------
// MFMA flash attention (causal GQA).
// R5: q-tile pairing (i, 31-i) for uniform causal work.
// R6: XOR-swizzled LDS, P aliased into K buffer.
// R7: in-block split-K, 8 waves; group 0 = even K-tiles, group 1 = odd.
// R8: __launch_bounds__(512,2) (no forced spill) + K via global_load_lds
//     with pre-swizzled source (T21).
// R9 FIX: K-staging source geometry. gld16 writes chunk c=i*256+gtid at
//     LDS byte c*16; KPg stride is 128 u16 = 16 chunks/row, so the linear
//     dest is row = i*16 + (gtid>>4), col = (gtid&15)*8. Source must be
//     K[k0 + i*16 + (gtid>>4)] at pre-swizzled col
//     ((gtid&15) ^ ((gtid>>4)&7))*8.  (R8 wrongly used the stride-64
//     geometry: gtid>>3 / i*32 -> scrambled K, absmax 4.9.)
// ---------------------------------------------------------------------------
__global__ __launch_bounds__(512, 2) void attn_mfma(
    const u16* __restrict__ qb, const u16* __restrict__ kb,
    const u16* __restrict__ vb, u16* __restrict__ ao)
{
    // 64 KB: KP[2] (16 KB each; softmax P aliases low 8 KB), Vt[2] (16 KB each)
    __shared__ __align__(16) u16 smem[32768];

    const int tid  = threadIdx.x;
    const int gtid = tid & 255;        // id within group
    const int grp  = tid >> 8;         // 0: even tiles, 1: odd tiles
    const int wg   = (tid >> 6) & 3;   // wave within group
    const int lane = tid & 63;
    const int quad = lane >> 4;
    const int n16  = lane & 15;
    const int h    = blockIdx.y;
    const int g    = h >> 2;
    const int NQT  = S_LEN / 64;       // 32 q-tiles

    u16* KPg = smem + grp * 8192;            // 64 x 128 (stride 128)
    u16* Vtg = smem + 16384 + grp * 8192;    // 128 x 64 (stride 64)
    float* mrg = reinterpret_cast<float*>(smem);  // merge buffer (40 KB)

    const u16* kbase = kb + (size_t)g * S_LEN * HD;
    const u16* vbase = vb + (size_t)g * S_LEN * HD;
    const int xsw = (n16 & 7) << 3;   // read-side XOR swizzle (u16 units)

    // K staging (R9-corrected): call i, chunk c = i*256 + gtid ->
    //   LDS row = i*16 + (gtid>>4), col = (gtid&15)*8 (linear dest);
    //   source col pre-swizzled so LDS[row][c] = K[row][c ^ ((row&7)<<3)].
    const int krow = gtid >> 4;                                // 0..15
    const int kcol = ((gtid & 15) ^ ((gtid >> 4) & 7)) << 3;   // pre-swizzled
    u16* kdst = KPg + (size_t)(wg * 64) * 8;                   // + i*256*8

    for (int half = 0; half < 2; ++half) {
        const int qt = half ? (NQT - 1 - blockIdx.x) : blockIdx.x;
        const int q0 = qt * 64;

        bf16x8 qf[4];
        {
            const u16* qrow = qb + ((size_t)h * S_LEN + q0 + wg * 16 + n16) * HD;
#pragma unroll
            for (int s = 0; s < 4; ++s)
                qf[s] = *reinterpret_cast<const bf16x8*>(qrow + s * 32 + quad * 8);
        }

        f32x4 of[8] = {};
        float mrow[4], lrow[4];
#pragma unroll
        for (int r = 0; r < 4; ++r) { mrow[r] = -1e30f; lrow[r] = 0.0f; }

        uint4 vreg[4];
        auto load_v = [&](int k0) {
#pragma unroll
            for (int i = 0; i < 4; ++i)
                vreg[i] = *reinterpret_cast<const uint4*>(
                    vbase + (size_t)(k0 + lane) * HD + wg * 8 + i * 32);
        };
        load_v(grp * 64);   // prologue: this group's first tile

        const int ntiles = qt + 1;
        const int nIt = (ntiles + 1) >> 1;
        for (int it = 0; it < nIt; ++it) {
            const int kt = 2 * it + grp;
            const bool act = (kt < ntiles);

            __syncthreads();   // prev tile's PV / merge reads done; LDS free
            if (act) {
                const int k0 = kt * 64;
                // K: async global->LDS, inverse-swizzled source, linear dest
#pragma unroll
                for (int i = 0; i < 4; ++i)
                    gld16(kbase + (size_t)(k0 + i * 16 + krow) * HD + kcol,
                          kdst + (size_t)(i * 256) * 8);
                // V regs -> LDS transposed (swizzled)
#pragma unroll
                for (int i = 0; i < 4; ++i) {
                    const int d0 = wg * 8 + i * 32;
                    const u32 vw[4] = {vreg[i].x, vreg[i].y, vreg[i].z, vreg[i].w};
#pragma unroll
                    for (int t = 0; t < 4; ++t) {
                        const int r0 = d0 + 2 * t;
                        Vtg[r0 * 64 + (lane ^ ((r0 & 7) << 3))]             = (u16)(vw[t] & 0xffff);
                        Vtg[(r0 + 1) * 64 + (lane ^ (((r0 + 1) & 7) << 3))] = (u16)(vw[t] >> 16);
                    }
                }
            }
            __syncthreads();   // staging visible (compiler drains vmcnt/lgkm)
            // prefetch this group's next tile (kt+2) under compute
            if (kt + 2 < ntiles) load_v((kt + 2) * 64);

            f32x4 sc[4] = {};
            if (act) {
#pragma unroll
                for (int s = 0; s < 4; ++s) {
#pragma unroll
                    for (int t = 0; t < 4; ++t) {
                        bf16x8 bf = *reinterpret_cast<const bf16x8*>(
                            &KPg[(t * 16 + n16) * 128 + ((s * 32 + quad * 8) ^ xsw)]);
                        sc[t] = __builtin_amdgcn_mfma_f32_16x16x32_bf16(qf[s], bf, sc[t], 0, 0, 0);
                    }
                }
                if (kt == qt) {   // diagonal tile: causal mask
                    const int qbase = q0 + wg * 16 + quad * 4;
#pragma unroll
                    for (int t = 0; t < 4; ++t) {
                        int key = kt * 64 + t * 16 + n16;
#pragma unroll
                        for (int r = 0; r < 4; ++r)
                            if (key > qbase + r) sc[t][r] = -1e30f;
                    }
                }
            }

            __syncthreads();   // group's waves done reading K; P may overwrite

            if (act) {
#pragma unroll
                for (int r = 0; r < 4; ++r) {
                    float mx = fmaxf(fmaxf(sc[0][r], sc[1][r]), fmaxf(sc[2][r], sc[3][r]));
                    mx = fmaxf(mx, __shfl_xor(mx, 1));
                    mx = fmaxf(mx, __shfl_xor(mx, 2));
                    mx = fmaxf(mx, __shfl_xor(mx, 4));
                    mx = fmaxf(mx, __shfl_xor(mx, 8));
                    float mnew  = fmaxf(mrow[r], mx);
                    float alpha = __expf(mrow[r] - mnew);
                    float ls = 0.0f;
                    const int pr = quad * 4 + r;
#pragma unroll
                    for (int t = 0; t < 4; ++t) {
                        float p = __expf(sc[t][r] - mnew);
                        KPg[(wg * 16 + pr) * 64 + ((t * 16 + n16) ^ ((pr & 7) << 3))] = f2bf(p);
                        ls += p;
                    }
                    ls += __shfl_xor(ls, 1);
                    ls += __shfl_xor(ls, 2);
                    ls += __shfl_xor(ls, 4);
                    ls += __shfl_xor(ls, 8);
                    lrow[r] = lrow[r] * alpha + ls;
                    mrow[r] = mnew;
#pragma unroll
                    for (int nt = 0; nt < 8; ++nt) of[nt][r] *= alpha;
                }
                __threadfence_block();

#pragma unroll
                for (int s = 0; s < 2; ++s) {
                    bf16x8 af = *reinterpret_cast<const bf16x8*>(
                        &KPg[(wg * 16 + n16) * 64 + ((s * 32 + quad * 8) ^ xsw)]);
#pragma unroll
                    for (int nt = 0; nt < 8; ++nt) {
                        bf16x8 bf = *reinterpret_cast<const bf16x8*>(
                            &Vtg[(nt * 16 + n16) * 64 + ((s * 32 + quad * 8) ^ xsw)]);
                        of[nt] = __builtin_amdgcn_mfma_f32_16x16x32_bf16(af, bf, of[nt], 0, 0, 0);
                    }
                }
            }
        }

        // ---- merge the two groups' online-softmax partials, group 0 writes out
        __syncthreads();   // all PV reads done; LDS reusable as merge buffer
        if (grp == 1) {
            float* dst = mrg + ((size_t)(wg * 64 + lane)) * 40;
#pragma unroll
            for (int nt = 0; nt < 8; ++nt)
#pragma unroll
                for (int r = 0; r < 4; ++r) dst[nt * 4 + r] = of[nt][r];
#pragma unroll
            for (int r = 0; r < 4; ++r) { dst[32 + r] = mrow[r]; dst[36 + r] = lrow[r]; }
        }
        __syncthreads();
        if (grp == 0) {
            const float* src = mrg + ((size_t)(wg * 64 + lane)) * 40;
#pragma unroll
            for (int r = 0; r < 4; ++r) {
                const float mB = src[32 + r], lB = src[36 + r];
                const float m  = fmaxf(mrow[r], mB);
                const float a  = __expf(mrow[r] - m);
                const float b  = __expf(mB - m);
                const float inv = 1.0f / (lrow[r] * a + lB * b);
                u16* dst = ao + (size_t)(q0 + wg * 16 + quad * 4 + r) * (NH * HD) + h * HD + n16;
#pragma unroll
                for (int nt = 0; nt < 8; ++nt)
                    dst[nt * 16] = f2bf((of[nt][r] * a + src[nt * 4 + r] * b) * inv);
            }
        }
        __syncthreads();   // merge reads done before next half's staging
    }
}

// ---------------------------------------------------------------------------
// Fast-path workspace overlay (bytes), peak 92,274,688:
//   hb   [2048][4096] bf16 @ 0           (16.8M)  -> reused as qb after gemm1
//   wqkv [6144][4096] bf16 @ 16,777,216  (50.3M)  -> dead after gemm1:
//        ao @ 16,777,216 (16.8M) | kb @ 33,554,432 | vb @ 37,748,736
//   wo_b [4096][4096] bf16 @ 41,943,040  (33.5M)
//   qkv  [2048][6144] bf16 @ 67,108,864  (25.2M)  -> dead after rope
// ---------------------------------------------------------------------------
extern "C" void kernel_launch(void* const* d_in, const int* in_sizes, int n_in,
                              void* d_out, int out_size, void* d_ws, size_t ws_size,
                              hipStream_t stream)
{
    const float* h   = (const float*)d_in[0];
    const int*   pos = (const int*)d_in[1];
    const float* wq  = (const float*)d_in[2];
    const float* wk  = (const float*)d_in[3];
    const float* wv  = (const float*)d_in[4];
    const float* wo  = (const float*)d_in[5];

    char* ws = (char*)d_ws;

    if (ws_size >= 92274688ull) {
        // ---- fast path: bf16 weight pre-convert + 128-tile global_load_lds GEMM
        u16* hb     = (u16*)(ws);
        u16* wqkv_b = (u16*)(ws + 16777216);
        u16* ao     = (u16*)(ws + 16777216);
        u16* kb     = (u16*)(ws + 33554432);
        u16* vb     = (u16*)(ws + 37748736);
        u16* wo_b   = (u16*)(ws + 41943040);
        u16* qkv    = (u16*)(ws + 67108864);
        u16* qb     = hb;

        cvt_f32_bf16<<<4096, 256, 0, stream>>>(h, hb, 1048576);          // 8.4M elems
        cvt_f32_bf16<<<8192, 256, 0, stream>>>(wq, wqkv_b, 2097152);     // 16.8M
        cvt_f32_bf16<<<2048, 256, 0, stream>>>(wk, wqkv_b + 16777216, 524288);
        cvt_f32_bf16<<<2048, 256, 0, stream>>>(wv, wqkv_b + 20971520, 524288);

        gemm128<true><<<dim3(NQKV / 128, S_LEN / 128), 256, 0, stream>>>(
            hb, wqkv_b, qkv, HID, NQKV);
        rope_kernel<<<S_LEN, 256, 0, stream>>>(qkv, pos, qb, kb, vb);
        cvt_f32_bf16<<<8192, 256, 0, stream>>>(wo, wo_b, 2097152);       // 16.8M
        attn_mfma<<<dim3(S_LEN / 128, NH), 512, 0, stream>>>(qb, kb, vb, ao);
        gemm128<false><<<dim3(HID / 128, S_LEN / 128), 256, 0, stream>>>(
            ao, wo_b, d_out, NH * HD, HID);
    } else {
        // ---- fallback (R3 layout, 64 MB)
        u16* qkv = (u16*)(ws);
        u16* qb  = (u16*)(ws + 25165824);
        u16* kb  = (u16*)(ws + 41943040);
        u16* vb  = (u16*)(ws + 46137344);
        u16* ao  = (u16*)(ws + 50331648);

        dim3 g1(NQKV / 64, S_LEN / 64);
        gemm_bt<true, true><<<g1, 256, 0, stream>>>(
            h, wq, NH * HD, wk, NH * HD + NKV * HD, wv, qkv, HID, NQKV);
        rope_kernel<<<S_LEN, 256, 0, stream>>>(qkv, pos, qb, kb, vb);
        attn_mfma<<<dim3(S_LEN / 128, NH), 512, 0, stream>>>(qb, kb, vb, ao);
        dim3 g2(HID / 64, S_LEN / 64);
        gemm_bt<false, false><<<g2, 256, 0, stream>>>(
            ao, wo, HID, wo, HID, wo, d_out, NH * HD, HID);
    }
}